// Round 2
// baseline (582.759 us; speedup 1.0000x reference)
//
#include <hip/hip_runtime.h>

#define T_DIM 512
#define C_DIM 48

#if __has_builtin(__builtin_amdgcn_readlane)
#define READLANE(v, l) __builtin_amdgcn_readlane((v), (l))
#else
#define READLANE(v, l) __shfl((v), (l), 64)
#endif

// One 64-lane wave per batch element. Lane j owns tag j (j<48).
// Forward: lane j computes argmax_i(score[i] + trans[i][j]) with exact
// lowest-i tie-break (4 contiguous chains + ordered merge), backpointers in LDS.
// Backtrace: bp rows preloaded to VGPRs, serial chain via readlane (SGPR y),
// tags accumulated via per-lane cndmask, dumped to LDS per 64-step chunk.
// Output: coalesced float4 one-hot writes (4 rows per wave-iteration).

__global__ __launch_bounds__(64) void crf_viterbi(
    const float* __restrict__ pot,     // [B][T][C]
    const int*   __restrict__ seqlen,  // [B][1]
    const float* __restrict__ trans,   // [C][C]
    float*       __restrict__ out)     // [B][T][C] one-hot f32
{
    const int b   = blockIdx.x;
    const int tid = threadIdx.x;
    const int jj  = (tid < C_DIM) ? tid : (C_DIM - 1);  // clamped for safe loads

    __shared__ float sc[2][C_DIM];                      // double-buffered scores
    __shared__ unsigned char bp[T_DIM][C_DIM];          // rows 1..L-1 used
    __shared__ __align__(4) unsigned char tags[T_DIM];

    const float* potb = pot + (size_t)b * (T_DIM * C_DIM);
    const int L   = seqlen[b];          // in [1, 511]
    const int thi = L - 1;

    // preload transitions column j into registers (clamped col for lanes >=48)
    float tc[C_DIM];
#pragma unroll
    for (int i = 0; i < C_DIM; ++i) tc[i] = trans[i * C_DIM + jj];

    // init: score = potentials[:,0]
    float score0 = potb[jj];
    if (tid < C_DIM) sc[0][tid] = score0;
    __syncthreads();

    int cur = 0;
    for (int t = 1; t < L; ++t) {
        const float potv = potb[t * C_DIM + jj];   // prefetch; used at end of step
        const float* s = sc[cur];

        // 4 contiguous chains over i: [0,12) [12,24) [24,36) [36,48)
        float v0, v1, v2, v3;
        int   a0, a1, a2, a3;
        {
            float4 sA = *(const float4*)(s + 0);
            float4 sB = *(const float4*)(s + 12);
            float4 sC = *(const float4*)(s + 24);
            float4 sD = *(const float4*)(s + 36);
            v0 = sA.x + tc[0];  a0 = 0;
            v1 = sB.x + tc[12]; a1 = 12;
            v2 = sC.x + tc[24]; a2 = 24;
            v3 = sD.x + tc[36]; a3 = 36;
            float t0, t1, t2, t3;
            t0 = sA.y + tc[1];  if (t0 > v0) { v0 = t0; a0 = 1;  }
            t1 = sB.y + tc[13]; if (t1 > v1) { v1 = t1; a1 = 13; }
            t2 = sC.y + tc[25]; if (t2 > v2) { v2 = t2; a2 = 25; }
            t3 = sD.y + tc[37]; if (t3 > v3) { v3 = t3; a3 = 37; }
            t0 = sA.z + tc[2];  if (t0 > v0) { v0 = t0; a0 = 2;  }
            t1 = sB.z + tc[14]; if (t1 > v1) { v1 = t1; a1 = 14; }
            t2 = sC.z + tc[26]; if (t2 > v2) { v2 = t2; a2 = 26; }
            t3 = sD.z + tc[38]; if (t3 > v3) { v3 = t3; a3 = 38; }
            t0 = sA.w + tc[3];  if (t0 > v0) { v0 = t0; a0 = 3;  }
            t1 = sB.w + tc[15]; if (t1 > v1) { v1 = t1; a1 = 15; }
            t2 = sC.w + tc[27]; if (t2 > v2) { v2 = t2; a2 = 27; }
            t3 = sD.w + tc[39]; if (t3 > v3) { v3 = t3; a3 = 39; }
        }
#pragma unroll
        for (int m = 1; m < 3; ++m) {
            float4 sA = *(const float4*)(s + m * 4);
            float4 sB = *(const float4*)(s + 12 + m * 4);
            float4 sC = *(const float4*)(s + 24 + m * 4);
            float4 sD = *(const float4*)(s + 36 + m * 4);
            float t0, t1, t2, t3;
            t0 = sA.x + tc[m*4+0];    if (t0 > v0) { v0 = t0; a0 = m*4+0; }
            t1 = sB.x + tc[m*4+12];   if (t1 > v1) { v1 = t1; a1 = m*4+12; }
            t2 = sC.x + tc[m*4+24];   if (t2 > v2) { v2 = t2; a2 = m*4+24; }
            t3 = sD.x + tc[m*4+36];   if (t3 > v3) { v3 = t3; a3 = m*4+36; }
            t0 = sA.y + tc[m*4+1];    if (t0 > v0) { v0 = t0; a0 = m*4+1; }
            t1 = sB.y + tc[m*4+13];   if (t1 > v1) { v1 = t1; a1 = m*4+13; }
            t2 = sC.y + tc[m*4+25];   if (t2 > v2) { v2 = t2; a2 = m*4+25; }
            t3 = sD.y + tc[m*4+37];   if (t3 > v3) { v3 = t3; a3 = m*4+37; }
            t0 = sA.z + tc[m*4+2];    if (t0 > v0) { v0 = t0; a0 = m*4+2; }
            t1 = sB.z + tc[m*4+14];   if (t1 > v1) { v1 = t1; a1 = m*4+14; }
            t2 = sC.z + tc[m*4+26];   if (t2 > v2) { v2 = t2; a2 = m*4+26; }
            t3 = sD.z + tc[m*4+38];   if (t3 > v3) { v3 = t3; a3 = m*4+38; }
            t0 = sA.w + tc[m*4+3];    if (t0 > v0) { v0 = t0; a0 = m*4+3; }
            t1 = sB.w + tc[m*4+15];   if (t1 > v1) { v1 = t1; a1 = m*4+15; }
            t2 = sC.w + tc[m*4+27];   if (t2 > v2) { v2 = t2; a2 = m*4+27; }
            t3 = sD.w + tc[m*4+39];   if (t3 > v3) { v3 = t3; a3 = m*4+39; }
        }
        // ordered merge: lower-index chain wins ties (strict > when taking higher chain)
        float vA = v0; int aA = a0;
        if (v1 > vA) { vA = v1; aA = a1; }
        float vB = v2; int aB = a2;
        if (v3 > vB) { vB = v3; aB = a3; }
        if (vB > vA) { vA = vB; aA = aB; }

        const float ns = vA + potv;
        const int nxt = cur ^ 1;
        if (tid < C_DIM) {
            sc[nxt][tid] = ns;
            bp[t][tid] = (unsigned char)aA;
        }
        cur = nxt;
        __syncthreads();
    }
    __syncthreads();

    // last_tag = argmax over final scores (all lanes redundantly, broadcast reads)
    const float* fs = sc[cur];
    float bv = fs[0];
    int   bi = 0;
#pragma unroll
    for (int i = 1; i < C_DIM; ++i) {
        float v = fs[i];
        if (v > bv) { bv = v; bi = i; }
    }
    const int last_tag = __builtin_amdgcn_readfirstlane(bi);

    // prefill tags[t] = last_tag for t in [L, T)
    for (int t = L + tid; t < T_DIM; t += 64) tags[t] = (unsigned char)last_tag;

    // serial backtrace: for t = thi..1: tags[t] = y; y = bp[t][y];  then tags[0] = y
    int y = last_tag;  // uniform (SGPR)
    for (int c0 = (thi >> 6) << 6; c0 >= 0; c0 -= 64) {
        // preload rows c0..c0+63: lane tid holds bp[c0+k][tid] (clamped lane)
        int row[64];
#pragma unroll
        for (int k = 0; k < 64; ++k) row[k] = bp[c0 + k][jj];

        int vacc = 0;
#pragma unroll
        for (int k = 63; k >= 0; --k) {
            const int t = c0 + k;
            vacc = (tid == k) ? y : vacc;                        // tags[t] = y (lane k)
            const int ynew = READLANE(row[k], y);
            if ((unsigned)(t - 1) < (unsigned)thi) y = ynew;     // update only for t in [1, thi]
        }
        const int tk = c0 + tid;
        if (tk <= thi) tags[tk] = (unsigned char)(vacc & 0xff);
    }
    __syncthreads();

    // emit one-hot: 4 rows (t) per iteration, 48 lanes x float4 = 768B coalesced
    if (tid < C_DIM) {
        const int r = tid / 12;          // row-in-group 0..3
        const int q = tid - r * 12;      // float4 slot 0..11
        const int cbase = q * 4;
        float* ob = out + (size_t)b * (T_DIM * C_DIM);
        for (int t0 = 0; t0 < T_DIM; t0 += 4) {
            const unsigned int tg4 = *(const unsigned int*)&tags[t0];
            const int mytag = (int)((tg4 >> (r * 8)) & 0xffu);
            float4 v;
            v.x = (cbase + 0 == mytag) ? 1.0f : 0.0f;
            v.y = (cbase + 1 == mytag) ? 1.0f : 0.0f;
            v.z = (cbase + 2 == mytag) ? 1.0f : 0.0f;
            v.w = (cbase + 3 == mytag) ? 1.0f : 0.0f;
            *(float4*)(ob + (size_t)(t0 + r) * C_DIM + cbase) = v;
        }
    }
}

extern "C" void kernel_launch(void* const* d_in, const int* in_sizes, int n_in,
                              void* d_out, int out_size, void* d_ws, size_t ws_size,
                              hipStream_t stream) {
    const float* pot    = (const float*)d_in[0];
    const int*   sl     = (const int*)d_in[1];
    const float* trans  = (const float*)d_in[2];
    float*       out    = (float*)d_out;
    const int B = in_sizes[1];  // sequence_lengths has B elements
    crf_viterbi<<<B, 64, 0, stream>>>(pot, sl, trans, out);
}

// Round 3
// 451.187 us; speedup vs baseline: 1.2916x; 1.2916x over previous
//
#include <hip/hip_runtime.h>

#define T_DIM 512
#define C_DIM 48
#define BPS   64          // bp row stride (padded to 64 so all lanes store)
#define CH    4           // prefetch chunk (distance 4..8 steps)

#if __has_builtin(__builtin_amdgcn_readlane)
#define READLANE(v, l) __builtin_amdgcn_readlane((v), (l))
#else
#define READLANE(v, l) __shfl((v), (l), 64)
#endif

// Compiler-level ordering fence for single-wave LDS communication.
// DS ops from one wave execute in order in the LDS pipeline; we only need to
// stop the compiler from reordering/caching across the step boundary.
#if __has_builtin(__builtin_amdgcn_wave_barrier)
#define WAVE_SYNC() do { __asm__ __volatile__("" ::: "memory"); __builtin_amdgcn_wave_barrier(); } while (0)
#else
#define WAVE_SYNC() __asm__ __volatile__("" ::: "memory")
#endif

// One Viterbi step: lane j computes argmax_i(score[i] + trans[i][j]) with
// exact lowest-i tie-break (4 contiguous chains, strict >, ordered merge).
#define VSTEP(T_, PV_) do {                                                  \
    const float* s_ = sc[cur];                                               \
    float sv[C_DIM];                                                         \
    _Pragma("unroll")                                                        \
    for (int m_ = 0; m_ < C_DIM / 4; ++m_)                                   \
        *(float4*)(sv + 4 * m_) = *(const float4*)(s_ + 4 * m_);             \
    float v0 = sv[0]  + tc[0];  int a0 = 0;                                  \
    float v1 = sv[12] + tc[12]; int a1 = 12;                                 \
    float v2 = sv[24] + tc[24]; int a2 = 24;                                 \
    float v3 = sv[36] + tc[36]; int a3 = 36;                                 \
    _Pragma("unroll")                                                        \
    for (int c_ = 1; c_ < 12; ++c_) {                                        \
        float t0_ = sv[c_]      + tc[c_];      if (t0_ > v0) { v0 = t0_; a0 = c_;      } \
        float t1_ = sv[12 + c_] + tc[12 + c_]; if (t1_ > v1) { v1 = t1_; a1 = 12 + c_; } \
        float t2_ = sv[24 + c_] + tc[24 + c_]; if (t2_ > v2) { v2 = t2_; a2 = 24 + c_; } \
        float t3_ = sv[36 + c_] + tc[36 + c_]; if (t3_ > v3) { v3 = t3_; a3 = 36 + c_; } \
    }                                                                        \
    float vA = v0; int aA = a0;                                              \
    if (v1 > vA) { vA = v1; aA = a1; }                                       \
    float vB = v2; int aB = a2;                                              \
    if (v3 > vB) { vB = v3; aB = a3; }                                       \
    if (vB > vA) { vA = vB; aA = aB; }                                       \
    const float ns_ = vA + (PV_);                                            \
    const int nxt_ = cur ^ 1;                                                \
    sc[nxt_][tid] = ns_;                 /* all 64 lanes; 48..63 hit pad */  \
    bp[(T_) * BPS + tid] = (unsigned char)aA;                                \
    cur = nxt_;                                                              \
    WAVE_SYNC();                                                             \
} while (0)

__global__ __launch_bounds__(64) void crf_viterbi(
    const float* __restrict__ pot,     // [B][T][C]
    const int*   __restrict__ seqlen,  // [B][1]
    const float* __restrict__ trans,   // [C][C]
    float*       __restrict__ out)     // [B][T][C] one-hot f32
{
    const int b   = blockIdx.x;
    const int tid = threadIdx.x;
    const int jj  = (tid < C_DIM) ? tid : (C_DIM - 1);  // clamped for safe loads

    __shared__ float sc[2][64];                          // padded to 64 lanes
    __shared__ unsigned char bp[T_DIM * BPS];            // rows 1..L-1 used
    __shared__ __align__(4) unsigned char tags[T_DIM];

    const float* potb = pot + (size_t)b * (T_DIM * C_DIM);
    const int L   = seqlen[b];          // in [1, 511]
    const int thi = L - 1;

    // transitions column j in registers (clamped col for lanes >= 48)
    float tc[C_DIM];
#pragma unroll
    for (int i = 0; i < C_DIM; ++i) tc[i] = trans[i * C_DIM + jj];

    // init: score = potentials[:,0]
    sc[0][tid] = potb[jj];
    WAVE_SYNC();

    int cur = 0;
    const float* pp = potb + jj;

    // software-pipelined forward loop: prefetch chunk CH ahead (clamped rows)
    float pb[CH];
#pragma unroll
    for (int k = 0; k < CH; ++k) {
        int tt = 1 + k; if (tt > T_DIM - 1) tt = T_DIM - 1;
        pb[k] = pp[tt * C_DIM];
    }
    for (int t0 = 1; t0 < L; t0 += CH) {
        float nb[CH];
#pragma unroll
        for (int k = 0; k < CH; ++k) {
            int tt = t0 + CH + k; if (tt > T_DIM - 1) tt = T_DIM - 1;
            nb[k] = pp[tt * C_DIM];
        }
#pragma unroll
        for (int k = 0; k < CH; ++k) {
            const int t = t0 + k;
            if (t >= L) break;           // wave-uniform branch
            VSTEP(t, pb[k]);
        }
#pragma unroll
        for (int k = 0; k < CH; ++k) pb[k] = nb[k];
    }
    __syncthreads();   // phase boundary (once; negligible)

    // last_tag = argmax over final scores (all lanes redundantly, broadcast reads)
    const float* fs = sc[cur];
    float bv = fs[0];
    int   bi = 0;
#pragma unroll
    for (int i = 1; i < C_DIM; ++i) {
        float v = fs[i];
        if (v > bv) { bv = v; bi = i; }
    }
    const int last_tag = __builtin_amdgcn_readfirstlane(bi);

    // prefill tags[t] = last_tag for t in [L, T)
    for (int t = L + tid; t < T_DIM; t += 64) tags[t] = (unsigned char)last_tag;

    // serial backtrace: for t = thi..1: tags[t] = y; y = bp[t][y];  then tags[0] = y
    int y = last_tag;  // wave-uniform (SGPR)
    for (int c0 = (thi >> 6) << 6; c0 >= 0; c0 -= 64) {
        int row[64];   // lane tid holds bp[c0+k][tid] for k = tid? no: row[k] across k
#pragma unroll
        for (int k = 0; k < 64; ++k) row[k] = bp[(c0 + k) * BPS + jj];

        int vacc = 0;
#pragma unroll
        for (int k = 63; k >= 0; --k) {
            const int t = c0 + k;
            vacc = (tid == k) ? y : vacc;                        // tags[t] = y (lane k)
            const int ynew = READLANE(row[k], y);
            if ((unsigned)(t - 1) < (unsigned)thi) y = ynew;     // update only for t in [1, thi]
        }
        const int tk = c0 + tid;
        if (tk <= thi) tags[tk] = (unsigned char)(vacc & 0xff);
    }
    __syncthreads();   // phase boundary

    // emit one-hot: 4 rows (t) per iteration, 48 lanes x float4 = 768B coalesced
    if (tid < C_DIM) {
        const int r = tid / 12;          // row-in-group 0..3
        const int q = tid - r * 12;      // float4 slot 0..11
        const int cbase = q * 4;
        float* ob = out + (size_t)b * (T_DIM * C_DIM);
        for (int t0 = 0; t0 < T_DIM; t0 += 4) {
            const unsigned int tg4 = *(const unsigned int*)&tags[t0];
            const int mytag = (int)((tg4 >> (r * 8)) & 0xffu);
            float4 v;
            v.x = (cbase + 0 == mytag) ? 1.0f : 0.0f;
            v.y = (cbase + 1 == mytag) ? 1.0f : 0.0f;
            v.z = (cbase + 2 == mytag) ? 1.0f : 0.0f;
            v.w = (cbase + 3 == mytag) ? 1.0f : 0.0f;
            *(float4*)(ob + (size_t)(t0 + r) * C_DIM + cbase) = v;
        }
    }
}

extern "C" void kernel_launch(void* const* d_in, const int* in_sizes, int n_in,
                              void* d_out, int out_size, void* d_ws, size_t ws_size,
                              hipStream_t stream) {
    const float* pot    = (const float*)d_in[0];
    const int*   sl     = (const int*)d_in[1];
    const float* trans  = (const float*)d_in[2];
    float*       out    = (float*)d_out;
    const int B = in_sizes[1];  // sequence_lengths has B elements
    crf_viterbi<<<B, 64, 0, stream>>>(pot, sl, trans, out);
}